// Round 1
// baseline (329.623 us; speedup 1.0000x reference)
//
#include <hip/hip_runtime.h>

typedef float f4 __attribute__((ext_vector_type(4)));

#define Gn 4
#define Bn 2
#define Tn 32
#define Cn 128
#define CG 32      // channels per head-group
#define Hn 64
#define Wn 64
#define HC 16
#define WC 16

// block = (g, b, h, whalf); 256 threads; thread tile = 4q x 4c x 4w (float4 over w)
__global__ __launch_bounds__(256, 3)
void temporal_agg_kernel(const float* __restrict__ x,
                         const float* __restrict__ attn,
                         float* __restrict__ out) {
    const int bid   = blockIdx.x;
    const int whalf = bid & 1;
    const int h     = (bid >> 1) & 63;
    const int b     = (bid >> 7) & 1;
    const int g     = bid >> 8;

    const int tid = threadIdx.x;

    // half-pixel h interpolation: src = 0.25*h - 0.375
    const float chf = 0.25f * (float)h - 0.375f;
    const float h0f = floorf(chf);
    const float fh  = chf - h0f;
    int h0 = (int)h0f;
    int h1 = h0 + 1;
    h0 = min(max(h0, 0), HC - 1);
    h1 = min(max(h1, 0), HC - 1);

    // Ah[k][j][q]: h-interpolated coarse attn, j = coarse-w col (10 cols incl. halo),
    // q fastest (padded 32->36 so each [k][j] row is 16B-aligned, <=2-way banks)
    __shared__ float Ah[Tn][10][36];

    // ---- phase 1: global -> LDS, h-lerp, transpose to q-fast ----
    const int wcb = whalf * 8 - 1;  // coarse col of j=0 (may be -1 -> clamped dup)
    const float* abase = attn + (size_t)(g * Bn + b) * (Tn * Tn * HC * WC);
    #pragma unroll 8
    for (int i = 0; i < 64; ++i) {
        int idx = tid + 256 * i;      // [0, 16384)
        int wc = idx & 15;
        int k  = (idx >> 4) & 31;
        int q  = idx >> 9;
        const float* p = abase + (size_t)(q * Tn + k) * (HC * WC);
        float v0 = p[h0 * WC + wc];
        float v1 = p[h1 * WC + wc];
        float ah = v0 + fh * (v1 - v0);
        int j = wc - wcb;
        if (j >= 0 && j < 10) Ah[k][j][q] = ah;
        if (whalf == 0 && wc == 0)  Ah[k][0][q] = ah;  // clamp(-1) -> col 0
        if (whalf == 1 && wc == 15) Ah[k][9][q] = ah;  // clamp(16) -> col 15
    }
    __syncthreads();

    // ---- phase 2: per-pixel temporal matmul ----
    const int qslot = tid & 7;         // 8 * 4 = 32 q
    const int wl    = (tid >> 3) & 7;  // 8 * 4 = 32 fine w in this half
    const int cslot = tid >> 6;        // 4 * 4 = 16 c per chalf pass
    const int q0    = qslot * 4;
    const int wfine = whalf * 32 + wl * 4;
    const int off_hw = h * Wn + wfine;

    for (int chalf = 0; chalf < 2; ++chalf) {
        f4 acc[4][4];
        #pragma unroll
        for (int qq = 0; qq < 4; ++qq)
            #pragma unroll
            for (int cc = 0; cc < 4; ++cc)
                acc[qq][cc] = (f4)0.0f;

        const int cbase = g * CG + chalf * 16 + cslot * 4;
        const float* xb = x + (size_t)b * (Tn * Cn * Hn * Wn)
                            + (size_t)cbase * (Hn * Wn) + off_hw;

        #pragma unroll 2
        for (int k = 0; k < Tn; ++k) {
            // A taps: coarse cols wl, wl+1, wl+2 cover fine w = 4*wlg + {0..3}
            f4 t0 = *(const f4*)&Ah[k][wl    ][q0];
            f4 t1 = *(const f4*)&Ah[k][wl + 1][q0];
            f4 t2 = *(const f4*)&Ah[k][wl + 2][q0];

            f4 xv[4];
            const float* xk = xb + (size_t)k * (Cn * Hn * Wn);
            #pragma unroll
            for (int cc = 0; cc < 4; ++cc)
                xv[cc] = *(const f4*)(xk + cc * (Hn * Wn));

            #pragma unroll
            for (int qq = 0; qq < 4; ++qq) {
                f4 a;
                a.x = 0.375f * t0[qq] + 0.625f * t1[qq];
                a.y = 0.125f * t0[qq] + 0.875f * t1[qq];
                a.z = 0.875f * t1[qq] + 0.125f * t2[qq];
                a.w = 0.625f * t1[qq] + 0.375f * t2[qq];
                #pragma unroll
                for (int cc = 0; cc < 4; ++cc)
                    acc[qq][cc] += a * xv[cc];
            }
        }

        #pragma unroll
        for (int qq = 0; qq < 4; ++qq) {
            const int q = q0 + qq;
            float* ob = out + ((size_t)(b * Tn + q) * Cn + cbase) * (Hn * Wn) + off_hw;
            #pragma unroll
            for (int cc = 0; cc < 4; ++cc)
                *(f4*)(ob + cc * (Hn * Wn)) = acc[qq][cc];
        }
    }
}

extern "C" void kernel_launch(void* const* d_in, const int* in_sizes, int n_in,
                              void* d_out, int out_size, void* d_ws, size_t ws_size,
                              hipStream_t stream) {
    const float* x    = (const float*)d_in[0];
    const float* attn = (const float*)d_in[1];
    float* out        = (float*)d_out;
    temporal_agg_kernel<<<dim3(Gn * Bn * Hn * 2), dim3(256), 0, stream>>>(x, attn, out);
}